// Round 11
// baseline (22.000 us; speedup 1.0000x reference)
//
#include <hip/hip_runtime.h>
#include <math.h>

#define B_   8
#define C_   4
#define H_   96
#define W_   96
#define HW_  9216
#define NBINS 18052              // exact d2 values 0..18050 (+inf case via svlo=-1)
#define NH32 ((NBINS + 1) / 2)   // 9026 packed words, 2 x u16 counters each
#define NT   1024                // threads per block (16 waves)
#define NW   16                  // waves per block
#define NGRP 1152                // 8-pixel groups (HW/8)
#define NBLK 48                  // 8 batches x 3 non-ignore classes x 2 dirs
#define HOT  128                 // bins < HOT go to per-wave private hists

// One block per (b, c in {1,2,3}, dir). dir==0: fwd (query=pred, target=label)
//                                      dir==1: rev (query=label, target=pred)
__global__ __launch_bounds__(NT) void hd_main(const float* __restrict__ preds,
                                              const int*   __restrict__ labels,
                                              float* __restrict__ frws)
{
    __shared__ unsigned char  qmb[NGRP];             // query mask bits (bit j of byte g = px 8g+j)
    __shared__ unsigned char  tmb[NGRP];             // target mask bits
    __shared__ unsigned short g2u[HW_];              // per-row 1D dist^2 (u16)
    __shared__ unsigned int   h32[NH32];             // packed u16 histogram (overflow bins >= HOT)
    __shared__ unsigned int   whist[NW * (HOT / 2)]; // per-wave packed u16 hot hists (4 KB)
    __shared__ int twv[NW], qwv[NW], zwv[NW], bwv[NW]; // per-wave nT, nQ, n0, bmax

    const int bid = blockIdx.x;       // 0..47
    const int b   = bid / 6;
    const int rem = bid - b * 6;
    const int c   = 1 + (rem >> 1);   // classes 1..3 only (class 0 is ignored downstream)
    const int dir = rem & 1;
    const int id  = ((b * 4 + c) << 1) | dir;        // 64-slot frws layout preserved
    const int tid = threadIdx.x;
    const int lane = tid & 63;
    const int wid  = tid >> 6;        // 0..15

    const float* Pb = preds  + (size_t)b * C_ * HW_;
    const int*   Lb = labels + (size_t)b * HW_;

    // clears (first used in step 3, i.e. after barrier 2)
    for (int i = tid; i < NH32; i += NT) h32[i] = 0u;
    whist[tid >> 0] = 0u;                            // NW*HOT/2 == NT exactly
    // ---- Step 1: vectorized argmax + masks (8 px/group), per-wave counts ----
    {
        int myT = 0, myQ = 0, myN0 = 0;
        #pragma unroll
        for (int k = 0; k < 2; ++k) {
            const int g = k * NT + tid;
            if (g < NGRP) {
                const int bp = g * 8;
                const float4 a0 = *(const float4*)(Pb + bp);
                const float4 b0 = *(const float4*)(Pb + bp + 4);
                const float4 a1 = *(const float4*)(Pb + HW_ + bp);
                const float4 b1 = *(const float4*)(Pb + HW_ + bp + 4);
                const float4 a2 = *(const float4*)(Pb + 2 * HW_ + bp);
                const float4 b2 = *(const float4*)(Pb + 2 * HW_ + bp + 4);
                const float4 a3 = *(const float4*)(Pb + 3 * HW_ + bp);
                const float4 b3 = *(const float4*)(Pb + 3 * HW_ + bp + 4);
                const int4   l0 = *(const int4*)(Lb + bp);
                const int4   l1 = *(const int4*)(Lb + bp + 4);
                unsigned tb = 0, qb = 0;
                // strict '>' keeps first max (jnp.argmax semantics)
                #define PX_(j, e0, e1, e2, e3, lj)                              \
                {   int bi = 0; float bv = (e0);                                \
                    if ((e1) > bv) { bv = (e1); bi = 1; }                       \
                    if ((e2) > bv) { bv = (e2); bi = 2; }                       \
                    if ((e3) > bv) { bv = (e3); bi = 3; }                       \
                    const bool pm = (bi == c);                                  \
                    const bool lm = ((lj) == c);                                \
                    const bool qm = dir ? lm : pm;                              \
                    const bool tm = dir ? pm : lm;                              \
                    tb |= (unsigned)tm << (j); qb |= (unsigned)qm << (j); }
                PX_(0, a0.x, a1.x, a2.x, a3.x, l0.x)
                PX_(1, a0.y, a1.y, a2.y, a3.y, l0.y)
                PX_(2, a0.z, a1.z, a2.z, a3.z, l0.z)
                PX_(3, a0.w, a1.w, a2.w, a3.w, l0.w)
                PX_(4, b0.x, b1.x, b2.x, b3.x, l1.x)
                PX_(5, b0.y, b1.y, b2.y, b3.y, l1.y)
                PX_(6, b0.z, b1.z, b2.z, b3.z, l1.z)
                PX_(7, b0.w, b1.w, b2.w, b3.w, l1.w)
                #undef PX_
                tmb[g] = (unsigned char)tb;
                qmb[g] = (unsigned char)qb;
                myT  += __popc(tb);
                myQ  += __popc(qb);
                myN0 += __popc(tb & qb);     // query px with d2 == 0
            }
        }
        #pragma unroll
        for (int d = 32; d >= 1; d >>= 1) {
            myT  += __shfl_xor(myT,  d, 64);
            myQ  += __shfl_xor(myQ,  d, 64);
            myN0 += __shfl_xor(myN0, d, 64);
        }
        if (lane == 0) { twv[wid] = myT; qwv[wid] = myQ; zwv[wid] = myN0; }
    }
    __syncthreads();                                     // barrier 1

    int nT = 0;
    #pragma unroll
    for (int w = 0; w < NW; ++w) nT += twv[w];           // broadcast LDS reads
    const int tEmpty = (nT == 0);

    // ---- Step 2: horizontal nearest-set-bit distance via clz/ctz ----
    // Row y = bytes tmb[12y..12y+11]; A = px 0..63, Bw = px 64..95.
    for (int k = 0; k < HW_ / NT; ++k) {
        const int p = k * NT + tid;
        const int y = p / W_;
        const int x = p - y * W_;
        const unsigned r0 = *(const unsigned*)(tmb + 12 * y);
        const unsigned r1 = *(const unsigned*)(tmb + 12 * y + 4);
        const unsigned r2 = *(const unsigned*)(tmb + 12 * y + 8);
        const unsigned long long A  = (unsigned long long)r0 |
                                      ((unsigned long long)r1 << 32);
        const unsigned long long Bw = r2;

        int dl = 1000, dr = 1000;
        if (x < 64) {
            const unsigned long long ml = A & ((2ull << x) - 1ull);   // bits <= x
            if (ml) dl = x - (63 - __builtin_clzll(ml));
            const unsigned long long mr = A & ~((1ull << x) - 1ull);  // bits >= x
            if (mr)      dr = __builtin_ctzll(mr) - x;
            else if (Bw) dr = 64 + __builtin_ctzll(Bw) - x;
        } else {
            const int xb = x - 64;                                    // 0..31
            const unsigned long long ml = Bw & ((2ull << xb) - 1ull);
            if (ml)     dl = x - (64 + 63 - __builtin_clzll(ml));
            else if (A) dl = x - (63 - __builtin_clzll(A));
            const unsigned long long mr = Bw & ~((1ull << xb) - 1ull);
            if (mr) dr = 64 + __builtin_ctzll(mr) - x;
        }
        const int g = min(dl, dr);
        g2u[p] = (g >= 96) ? (unsigned short)40000     // row empty: > any real d2
                           : (unsigned short)(g * g);
    }
    __syncthreads();                                     // barrier 2

    // ---- Step 3: exact column scan — speculative ±2 window + rare tail ----
    // Hot bins (< HOT) go to this wave's private hist; rest to shared h32.
    {
        int bmax = 0;
        unsigned int* wh = whist + wid * (HOT / 2);
        if (!tEmpty) {
            for (int k = 0; k < HW_ / NT; ++k) {
                const int p = k * NT + tid;
                const int byi = p >> 3, bsh = p & 7;
                if (!((qmb[byi] >> bsh) & 1)) continue;
                if ((tmb[byi] >> bsh) & 1) continue;     // d2 == 0, via popcount
                const int y = p / W_;
                const int x = p - y * W_;
                const int a0 = (int)g2u[p];
                const int a1 = (y >= 1)     ? (int)g2u[p - W_]     : 0x7FFF0000;
                const int a2 = (y + 1 < H_) ? (int)g2u[p + W_]     : 0x7FFF0000;
                const int a3 = (y >= 2)     ? (int)g2u[p - 2 * W_] : 0x7FFF0000;
                const int a4 = (y + 2 < H_) ? (int)g2u[p + 2 * W_] : 0x7FFF0000;
                int best = min(a0, min(min(a1 + 1, a2 + 1), min(a3 + 4, a4 + 4)));
                for (int off = 3; off < H_; ++off) {     // exact prune
                    const int o2 = off * off;
                    if (o2 >= best) break;
                    const int r1 = y - off;
                    const int r2 = y + off;
                    if (r1 >= 0) best = min(best, o2 + (int)g2u[r1 * W_ + x]);
                    if (r2 < H_) best = min(best, o2 + (int)g2u[r2 * W_ + x]);
                }
                bmax = max(bmax, best);
                const unsigned inc = 1u << ((best & 1) << 4);
                if (best < HOT) atomicAdd(&wh[best >> 1], inc);       // wave-private
                else            atomicAdd(&h32[best >> 1], inc);      // rare overflow
            }
        }
        #pragma unroll
        for (int d = 32; d >= 1; d >>= 1) bmax = max(bmax, __shfl_xor(bmax, d, 64));
        if (lane == 0) bwv[wid] = bmax;
    }
    __syncthreads();                                     // barrier 3 (last)

    if (wid != 0) return;                                // waves 1..15 done

    // ---- Step 4: single-wave exact rank selection over live bins ----
    int nQ = 0, n0s = 0, maxd2 = 0;
    #pragma unroll
    for (int w = 0; w < NW; ++w) {
        nQ += qwv[w]; n0s += zwv[w]; maxd2 = max(maxd2, bwv[w]);
    }
    const int h0x = tEmpty ? 0 : n0s;                    // bin-0 count via popcount

    int nm1 = nQ - 1; if (nm1 < 0) nm1 = 0;
    const float posf = 0.95f * (float)nm1;               // matches (q/100)*f32(n-1)
    const int lo = (int)floorf(posf);
    const int hi = (int)ceilf(posf);
    const float frac = posf - (float)lo;

    int svlo = -1, svhi = -1;
    if (!tEmpty) {
        int run = 0;
        for (int base = 0; base <= maxd2; base += 64) {  // striped rounds of 64 bins
            const int i = base + lane;
            int h = 0;
            if (i <= maxd2) {
                if (i == 0) {
                    h = h0x;
                } else if (i < HOT) {
                    const int wofs = i >> 1, hsh = (i & 1) << 4;
                    #pragma unroll
                    for (int w = 0; w < NW; ++w)
                        h += (int)((whist[w * (HOT / 2) + wofs] >> hsh) & 0xFFFFu);
                } else {
                    h = (int)((h32[i >> 1] >> ((i & 1) << 4)) & 0xFFFFu);
                }
            }
            int inc = h;
            #pragma unroll
            for (int d = 1; d < 64; d <<= 1) {
                const int t = __shfl_up(inc, d, 64);
                if (lane >= d) inc += t;
            }
            const int excl = run + inc - h;              // exclusive prefix of bin i
            if (h > 0) {
                if (excl <= lo && lo < excl + h) svlo = i;
                if (excl <= hi && hi < excl + h) svhi = i;
            }
            run += __shfl(inc, 63, 64);                  // add round total
        }
        #pragma unroll
        for (int d = 32; d >= 1; d >>= 1) {              // exactly one lane found each
            svlo = max(svlo, __shfl_xor(svlo, d, 64));
            svhi = max(svhi, __shfl_xor(svhi, d, 64));
        }
    }
    if (lane == 0) {
        // sv<0 (empty target or empty query) -> inf; literal reference arithmetic
        // (inf*0 -> nan semantics preserved)
        const float vlo = (svlo < 0) ? __builtin_inff() : (float)sqrt((double)svlo);
        const float vhi = (svhi < 0) ? __builtin_inff() : (float)sqrt((double)svhi);
        frws[id] = vlo * (1.0f - frac) + vhi * frac;
    }
}

// 18 threads, each computes one output element (identical float-op order to the
// validated serial version; class 0 is the ignore class -> contributes 0).
__global__ __launch_bounds__(64) void hd_fin(const float* __restrict__ frws,
                                             float* __restrict__ out)
{
    __shared__ float fr[64];
    const int tid = threadIdx.x;
    fr[tid] = frws[tid];                                 // parallel load (64 values)
    __syncthreads();
    if (tid >= 18) return;
    const int sec = tid / 6;                             // 0=MHD, 1=FHD, 2=RHD
    const int j   = tid - sec * 6;

    // per-class mean over batch for this section, c in 1..3 (c==0 -> 0.0f)
    auto classval = [&](int c) -> float {
        float s = 0.0f;
        for (int b = 0; b < 8; ++b) {
            const float f = fr[((b * 4 + c) << 1) + 0];
            const float r = fr[((b * 4 + c) << 1) + 1];
            float v;
            if (sec == 1)      v = f;
            else if (sec == 2) v = r;
            else {
                v = f > r ? f : r;
                if (f != f || r != r) v = f + r;        // NaN-propagating maximum
            }
            s += v;
        }
        return s / 8.0f;
    };

    float res;
    if (j < 4) {
        res = (j == 0) ? 0.0f : classval(j);
    } else {
        const float v1 = classval(1), v2 = classval(2), v3 = classval(3);
        if (j == 4) res = (0.0f + v1 + v2 + v3) / 4.0f;  // mean incl. zeroed class 0
        else        res = (v1 + v2 + v3) / 3.0f;         // mean excl. class 0
    }
    out[sec * 6 + j] = res;
}

extern "C" void kernel_launch(void* const* d_in, const int* in_sizes, int n_in,
                              void* d_out, int out_size, void* d_ws, size_t ws_size,
                              hipStream_t stream)
{
    const float* preds  = (const float*)d_in[0];
    const int*   labels = (const int*)d_in[1];
    float* frws = (float*)d_ws;                  // 64 floats staging (f,r per b,c)

    hipLaunchKernelGGL(hd_main, dim3(NBLK), dim3(NT), 0, stream,
                       preds, labels, frws);
    hipLaunchKernelGGL(hd_fin, dim3(1), dim3(64), 0, stream,
                       frws, (float*)d_out);
}

// Round 12
// 20.341 us; speedup vs baseline: 1.0815x; 1.0815x over previous
//
#include <hip/hip_runtime.h>
#include <math.h>

#define B_   8
#define C_   4
#define H_   96
#define W_   96
#define HW_  9216
#define NBINS 18052              // exact d2 values 0..18050 (+inf case via svlo=-1)
#define NH32 ((NBINS + 1) / 2)   // 9026 packed words, 2 x u16 counters each
#define NT   1024                // threads per block (16 waves)
#define NBLK 64                  // B*C*2
#define NW   16                  // waves per block
#define NGRP 1152                // 8-pixel groups (HW/8)

// One block per (b, c, dir). dir==0: fwd (query = pred set, target = label set)
//                            dir==1: rev (query = label set, target = pred set)
__global__ __launch_bounds__(NT) void hd_main(const float* __restrict__ preds,
                                              const int*   __restrict__ labels,
                                              float* __restrict__ frws)
{
    __shared__ unsigned char  qmb[NGRP];             // query mask bits (bit j of byte g = px 8g+j)
    __shared__ unsigned char  tmb[NGRP];             // target mask bits
    __shared__ unsigned short g2u[HW_];              // per-row 1D dist^2 (u16)
    __shared__ unsigned int   h32[NH32];             // packed 16-bit histogram
    __shared__ int twv[NW], qwv[NW], zwv[NW], bwv[NW]; // per-wave nT, nQ, n0, bmax

    const int id  = blockIdx.x;       // 0..63
    const int dir = id & 1;
    const int bc  = id >> 1;
    const int b   = bc >> 2;
    const int c   = bc & 3;
    const int tid = threadIdx.x;
    const int lane = tid & 63;
    const int wid  = tid >> 6;        // 0..15

    const float* Pb = preds  + (size_t)b * C_ * HW_;
    const int*   Lb = labels + (size_t)b * HW_;

    // hist clear (first used in step 3, after barrier 2)
    for (int i = tid; i < NH32; i += NT) h32[i] = 0u;

    // ---- Step 1: vectorized argmax + masks (8 px/group), per-wave counts ----
    {
        int myT = 0, myQ = 0, myN0 = 0;
        #pragma unroll
        for (int k = 0; k < 2; ++k) {
            const int g = k * NT + tid;
            if (g < NGRP) {
                const int bp = g * 8;
                const float4 a0 = *(const float4*)(Pb + bp);
                const float4 b0 = *(const float4*)(Pb + bp + 4);
                const float4 a1 = *(const float4*)(Pb + HW_ + bp);
                const float4 b1 = *(const float4*)(Pb + HW_ + bp + 4);
                const float4 a2 = *(const float4*)(Pb + 2 * HW_ + bp);
                const float4 b2 = *(const float4*)(Pb + 2 * HW_ + bp + 4);
                const float4 a3 = *(const float4*)(Pb + 3 * HW_ + bp);
                const float4 b3 = *(const float4*)(Pb + 3 * HW_ + bp + 4);
                const int4   l0 = *(const int4*)(Lb + bp);
                const int4   l1 = *(const int4*)(Lb + bp + 4);
                unsigned tb = 0, qb = 0;
                // strict '>' keeps first max (jnp.argmax semantics)
                #define PX_(j, e0, e1, e2, e3, lj)                              \
                {   int bi = 0; float bv = (e0);                                \
                    if ((e1) > bv) { bv = (e1); bi = 1; }                       \
                    if ((e2) > bv) { bv = (e2); bi = 2; }                       \
                    if ((e3) > bv) { bv = (e3); bi = 3; }                       \
                    const bool pm = (bi == c);                                  \
                    const bool lm = ((lj) == c);                                \
                    const bool qm = dir ? lm : pm;                              \
                    const bool tm = dir ? pm : lm;                              \
                    tb |= (unsigned)tm << (j); qb |= (unsigned)qm << (j); }
                PX_(0, a0.x, a1.x, a2.x, a3.x, l0.x)
                PX_(1, a0.y, a1.y, a2.y, a3.y, l0.y)
                PX_(2, a0.z, a1.z, a2.z, a3.z, l0.z)
                PX_(3, a0.w, a1.w, a2.w, a3.w, l0.w)
                PX_(4, b0.x, b1.x, b2.x, b3.x, l1.x)
                PX_(5, b0.y, b1.y, b2.y, b3.y, l1.y)
                PX_(6, b0.z, b1.z, b2.z, b3.z, l1.z)
                PX_(7, b0.w, b1.w, b2.w, b3.w, l1.w)
                #undef PX_
                tmb[g] = (unsigned char)tb;
                qmb[g] = (unsigned char)qb;
                myT  += __popc(tb);
                myQ  += __popc(qb);
                myN0 += __popc(tb & qb);     // query px with d2 == 0
            }
        }
        #pragma unroll
        for (int d = 32; d >= 1; d >>= 1) {
            myT  += __shfl_xor(myT,  d, 64);
            myQ  += __shfl_xor(myQ,  d, 64);
            myN0 += __shfl_xor(myN0, d, 64);
        }
        if (lane == 0) { twv[wid] = myT; qwv[wid] = myQ; zwv[wid] = myN0; }
    }
    __syncthreads();                                     // barrier 1

    int nT = 0;
    #pragma unroll
    for (int w = 0; w < NW; ++w) nT += twv[w];           // broadcast LDS reads
    const int tEmpty = (nT == 0);

    // ---- Step 2: horizontal nearest-set-bit distance via clz/ctz ----
    // Row y = bytes tmb[12y..12y+11]; A = px 0..63, Bw = px 64..95.
    for (int k = 0; k < HW_ / NT; ++k) {
        const int p = k * NT + tid;
        const int y = p / W_;
        const int x = p - y * W_;
        const unsigned r0 = *(const unsigned*)(tmb + 12 * y);
        const unsigned r1 = *(const unsigned*)(tmb + 12 * y + 4);
        const unsigned r2 = *(const unsigned*)(tmb + 12 * y + 8);
        const unsigned long long A  = (unsigned long long)r0 |
                                      ((unsigned long long)r1 << 32);
        const unsigned long long Bw = r2;

        int dl = 1000, dr = 1000;
        if (x < 64) {
            const unsigned long long ml = A & ((2ull << x) - 1ull);   // bits <= x
            if (ml) dl = x - (63 - __builtin_clzll(ml));
            const unsigned long long mr = A & ~((1ull << x) - 1ull);  // bits >= x
            if (mr)      dr = __builtin_ctzll(mr) - x;
            else if (Bw) dr = 64 + __builtin_ctzll(Bw) - x;
        } else {
            const int xb = x - 64;                                    // 0..31
            const unsigned long long ml = Bw & ((2ull << xb) - 1ull);
            if (ml)     dl = x - (64 + 63 - __builtin_clzll(ml));
            else if (A) dl = x - (63 - __builtin_clzll(A));
            const unsigned long long mr = Bw & ~((1ull << xb) - 1ull);
            if (mr) dr = 64 + __builtin_ctzll(mr) - x;
        }
        const int g = min(dl, dr);
        g2u[p] = (g >= 96) ? (unsigned short)40000     // row empty: > any real d2
                           : (unsigned short)(g * g);
    }
    __syncthreads();                                     // barrier 2

    // ---- Step 3: exact column scan — speculative ±2 window + rare tail ----
    {
        int bmax = 0;
        if (!tEmpty) {
            for (int k = 0; k < HW_ / NT; ++k) {
                const int p = k * NT + tid;
                const int byi = p >> 3, bsh = p & 7;
                if (!((qmb[byi] >> bsh) & 1)) continue;
                if ((tmb[byi] >> bsh) & 1) continue;     // d2 == 0, via popcount
                const int y = p / W_;
                const int x = p - y * W_;
                const int a0 = (int)g2u[p];
                const int a1 = (y >= 1)     ? (int)g2u[p - W_]     : 0x7FFF0000;
                const int a2 = (y + 1 < H_) ? (int)g2u[p + W_]     : 0x7FFF0000;
                const int a3 = (y >= 2)     ? (int)g2u[p - 2 * W_] : 0x7FFF0000;
                const int a4 = (y + 2 < H_) ? (int)g2u[p + 2 * W_] : 0x7FFF0000;
                int best = min(a0, min(min(a1 + 1, a2 + 1), min(a3 + 4, a4 + 4)));
                for (int off = 3; off < H_; ++off) {     // exact prune
                    const int o2 = off * off;
                    if (o2 >= best) break;
                    const int r1 = y - off;
                    const int r2 = y + off;
                    if (r1 >= 0) best = min(best, o2 + (int)g2u[r1 * W_ + x]);
                    if (r2 < H_) best = min(best, o2 + (int)g2u[r2 * W_ + x]);
                }
                bmax = max(bmax, best);
                atomicAdd(&h32[best >> 1], 1u << ((best & 1) << 4));  // [1,18050]
            }
        }
        #pragma unroll
        for (int d = 32; d >= 1; d >>= 1) bmax = max(bmax, __shfl_xor(bmax, d, 64));
        if (lane == 0) bwv[wid] = bmax;
    }
    __syncthreads();                                     // barrier 3 (last)

    if (wid != 0) return;                                // waves 1..15 done

    // ---- Step 4: single-wave exact rank selection over live bins ----
    int nQ = 0, n0s = 0, maxd2 = 0;
    #pragma unroll
    for (int w = 0; w < NW; ++w) {
        nQ += qwv[w]; n0s += zwv[w]; maxd2 = max(maxd2, bwv[w]);
    }
    const int h0x = tEmpty ? 0 : n0s;                    // bin-0 count via popcount

    int nm1 = nQ - 1; if (nm1 < 0) nm1 = 0;
    const float posf = 0.95f * (float)nm1;               // matches (q/100)*f32(n-1)
    const int lo = (int)floorf(posf);
    const int hi = (int)ceilf(posf);
    const float frac = posf - (float)lo;

    int svlo = -1, svhi = -1;
    if (!tEmpty) {
        int run = 0;
        for (int base = 0; base <= maxd2; base += 64) {  // striped rounds of 64 bins
            const int i = base + lane;
            int h = 0;
            if (i <= maxd2) {
                h = (int)((h32[i >> 1] >> ((i & 1) << 4)) & 0xFFFFu);
                if (i == 0) h += h0x;
            }
            int inc = h;
            #pragma unroll
            for (int d = 1; d < 64; d <<= 1) {
                const int t = __shfl_up(inc, d, 64);
                if (lane >= d) inc += t;
            }
            const int excl = run + inc - h;              // exclusive prefix of bin i
            if (h > 0) {
                if (excl <= lo && lo < excl + h) svlo = i;
                if (excl <= hi && hi < excl + h) svhi = i;
            }
            run += __shfl(inc, 63, 64);                  // add round total
        }
        #pragma unroll
        for (int d = 32; d >= 1; d >>= 1) {              // exactly one lane found each
            svlo = max(svlo, __shfl_xor(svlo, d, 64));
            svhi = max(svhi, __shfl_xor(svhi, d, 64));
        }
    }
    if (lane == 0) {
        // sv<0 (empty target or empty query) -> inf; literal reference arithmetic
        // (inf*0 -> nan semantics preserved)
        const float vlo = (svlo < 0) ? __builtin_inff() : (float)sqrt((double)svlo);
        const float vhi = (svhi < 0) ? __builtin_inff() : (float)sqrt((double)svhi);
        frws[id] = vlo * (1.0f - frac) + vhi * frac;
    }
}

__global__ __launch_bounds__(64) void hd_fin(const float* __restrict__ frws,
                                             float* __restrict__ out)
{
    __shared__ float fr[NBLK];
    const int tid = threadIdx.x;
    fr[tid] = frws[tid];                                 // parallel load (64 values)
    __syncthreads();
    if (tid == 0) {
        float F[4], R[4], M[4];
        for (int c = 0; c < 4; ++c) {
            if (c == 0) { F[c] = R[c] = M[c] = 0.0f; continue; }  // IGNORE class
            float sf = 0.0f, sr = 0.0f, sm = 0.0f;
            for (int b = 0; b < 8; ++b) {
                const float f = fr[((b * 4 + c) << 1) + 0];
                const float r = fr[((b * 4 + c) << 1) + 1];
                sf += f; sr += r;
                float m = f > r ? f : r;
                if (f != f || r != r) m = f + r;        // NaN-propagating maximum
                sm += m;
            }
            F[c] = sf / 8.0f; R[c] = sr / 8.0f; M[c] = sm / 8.0f;
        }
        // out = concat(MHD, FHD, RHD), each [c0..c3, mean(all), mean(excl c0)]
        float* o = out;
        o[0] = M[0]; o[1] = M[1]; o[2] = M[2]; o[3] = M[3];
        o[4] = (M[0] + M[1] + M[2] + M[3]) / 4.0f;
        o[5] = (M[1] + M[2] + M[3]) / 3.0f;
        o += 6;
        o[0] = F[0]; o[1] = F[1]; o[2] = F[2]; o[3] = F[3];
        o[4] = (F[0] + F[1] + F[2] + F[3]) / 4.0f;
        o[5] = (F[1] + F[2] + F[3]) / 3.0f;
        o += 6;
        o[0] = R[0]; o[1] = R[1]; o[2] = R[2]; o[3] = R[3];
        o[4] = (R[0] + R[1] + R[2] + R[3]) / 4.0f;
        o[5] = (R[1] + R[2] + R[3]) / 3.0f;
    }
}

extern "C" void kernel_launch(void* const* d_in, const int* in_sizes, int n_in,
                              void* d_out, int out_size, void* d_ws, size_t ws_size,
                              hipStream_t stream)
{
    const float* preds  = (const float*)d_in[0];
    const int*   labels = (const int*)d_in[1];
    float* frws = (float*)d_ws;                  // 64 floats staging (f,r per b,c)

    hipLaunchKernelGGL(hd_main, dim3(NBLK), dim3(NT), 0, stream,
                       preds, labels, frws);
    hipLaunchKernelGGL(hd_fin, dim3(1), dim3(64), 0, stream,
                       frws, (float*)d_out);
}